// Round 10
// baseline (283.813 us; speedup 1.0000x reference)
//
#include <hip/hip_runtime.h>

constexpr int Dd = 128;
constexpr float BN_EPS = 1e-12f;
constexpr float NEG_SLOPE = 0.2f;

using bf16x8 = __attribute__((ext_vector_type(8))) short;
using f32x4  = __attribute__((ext_vector_type(4))) float;

__device__ __forceinline__ ushort f2bf(float f) {
    unsigned u = __float_as_uint(f);
    return (ushort)((u + 0x7fffu + ((u >> 16) & 1u)) >> 16);
}
__device__ __forceinline__ float lrelu(float x) { return x > 0.f ? x : NEG_SLOPE * x; }

// ---------------- W prep + coarse-cnt zero + BN-const precompute ----------------
__global__ __launch_bounds__(256) void wprep_zero_kernel(
    const float* __restrict__ W, ushort* __restrict__ Wt, int* __restrict__ cntc,
    const float* __restrict__ bias, const float* __restrict__ gamma,
    const float* __restrict__ beta, const float* __restrict__ mean,
    const float* __restrict__ var, float* __restrict__ kA, float* __restrict__ kB)
{
    int t = threadIdx.x;
    if (blockIdx.x >= 2) {           // block 2: zero coarse counters + BN consts (both layers)
        cntc[t] = 0;
        float sc = gamma[t] * rsqrtf(var[t] + BN_EPS);
        kA[t] = sc;
        kB[t] = (bias[t] - mean[t]) * sc + beta[t];
        return;
    }
    __shared__ float lds[32][33];
    const float* Wl = W + (size_t)blockIdx.x * Dd * Dd;
    ushort* Wo = Wt + (size_t)blockIdx.x * Dd * Dd;
    int r = t >> 3, c4 = (t & 7) << 2;
    for (int tk = 0; tk < 4; ++tk)
    for (int tn = 0; tn < 4; ++tn) {
        int k0 = tk * 32, n0 = tn * 32;
        float4 v = *(const float4*)&Wl[(size_t)(k0 + r) * Dd + n0 + c4];
        lds[r][c4] = v.x; lds[r][c4 + 1] = v.y; lds[r][c4 + 2] = v.z; lds[r][c4 + 3] = v.w;
        __syncthreads();
        ushort4 o;
        o.x = f2bf(lds[c4 + 0][r]); o.y = f2bf(lds[c4 + 1][r]);
        o.z = f2bf(lds[c4 + 2][r]); o.w = f2bf(lds[c4 + 3][r]);
        *(ushort4*)&Wo[(size_t)(n0 + r) * Dd + k0 + c4] = o;
        __syncthreads();
    }
}

// ---------------- coarse scan (1 block) ----------------
__global__ __launch_bounds__(256) void coarse_scan_kernel(
    const int* __restrict__ cntc, int* __restrict__ base,
    int* __restrict__ cursor, int NB, int E)
{
    __shared__ int lds[256];
    int t = threadIdx.x;
    int v0 = (t < NB) ? cntc[t] : 0;
    lds[t] = v0;
    __syncthreads();
    for (int o = 1; o < 256; o <<= 1) {
        int v = (t >= o) ? lds[t - o] : 0;
        __syncthreads();
        lds[t] += v;
        __syncthreads();
    }
    int excl = lds[t] - v0;
    if (t < NB) { base[t] = excl; cursor[t] = excl; }
    if (t == 0) base[NB] = E;
}

// ---------------- partition: stage by bucket in LDS, coalesced flush ----------------
// packed = src | dst_lo<<16 | bucket<<24  (valid because N < 65536)
__global__ __launch_bounds__(256) void partition_kernel(
    const int* __restrict__ src, const int* __restrict__ dst,
    int* __restrict__ cursor, unsigned* __restrict__ gpart, int E)
{
    __shared__ int h[256], lb[256], gs[256], cur[256];
    __shared__ unsigned staged[4096];
    const int t = threadIdx.x;
    const int c0 = blockIdx.x * 4096;
    const int count = min(4096, E - c0);

    h[t] = 0; cur[t] = 0;
    __syncthreads();
#pragma unroll
    for (int j = 0; j < 16; ++j) {
        int idx = j * 256 + t;
        if (idx < count) atomicAdd(&h[dst[c0 + idx] >> 8], 1);
    }
    __syncthreads();
    {
        int v0 = h[t];
        lb[t] = v0;
        __syncthreads();
        for (int o = 1; o < 256; o <<= 1) {
            int v = (t >= o) ? lb[t - o] : 0;
            __syncthreads();
            lb[t] += v;
            __syncthreads();
        }
        lb[t] -= v0;
    }
    if (h[t]) gs[t] = atomicAdd(&cursor[t], h[t]);
    __syncthreads();
#pragma unroll
    for (int j = 0; j < 16; ++j) {
        int idx = j * 256 + t;
        if (idx < count) {
            int d = dst[c0 + idx], s = src[c0 + idx];
            int b = d >> 8;
            int pos = lb[b] + atomicAdd(&cur[b], 1);
            staged[pos] = (unsigned)s | ((unsigned)(d & 255) << 16) | ((unsigned)b << 24);
        }
    }
    __syncthreads();
#pragma unroll
    for (int j = 0; j < 16; ++j) {
        int idx = j * 256 + t;
        if (idx < count) {
            unsigned p = staged[idx];
            int b = p >> 24;
            gpart[gs[b] + (idx - lb[b])] = p;
        }
    }
}

// ---------------- per-bucket CSR finalize: rowptr + self-loops + ssrc ----------------
__global__ __launch_bounds__(256) void bucket_csr_kernel(
    const unsigned* __restrict__ gpart, const int* __restrict__ base,
    int* __restrict__ rowptr, int* __restrict__ ssrc, int N, int NB, int Etot)
{
    __shared__ int h[256], lb[256], cur[256];
    const int t = threadIdx.x;
    const int b = blockIdx.x;
    const int cb = base[b], ce = base[b + 1];
    const int cb2 = cb + b * 256;   // +1 self edge per node in earlier buckets
    const int cnt = ce - cb;

    h[t] = 0; cur[t] = 0;
    __syncthreads();
    for (int o = t; o < cnt; o += 256)
        atomicAdd(&h[(gpart[cb + o] >> 16) & 255], 1);
    __syncthreads();
    {
        int v0 = h[t];
        lb[t] = v0;
        __syncthreads();
        for (int o = 1; o < 256; o <<= 1) {
            int v = (t >= o) ? lb[t - o] : 0;
            __syncthreads();
            lb[t] += v;
            __syncthreads();
        }
        lb[t] -= v0;
    }
    int n0 = b * 256 + t;
    if (n0 < N) {
        int rp = cb2 + lb[t] + t;
        rowptr[n0] = rp;
        ssrc[rp] = n0;       // self-loop first
    }
    if (b == 0 && t == 0) rowptr[N] = Etot;
    __syncthreads();
    for (int o = t; o < cnt; o += 256) {
        unsigned p = gpart[cb + o];
        int n = (p >> 16) & 255;
        int pos = lb[n] + atomicAdd(&cur[n], 1);
        ssrc[cb2 + pos + n + 1] = (int)(p & 0xFFFFu);
    }
}

// ---------------- layer-0 GEMM (f32 in) fused with coarse hist ----------------
// blocks [0,nGemm): Hf = f16(x@W0), hs/hd; blocks [nGemm, nGemm+256): dst histogram.
__global__ __launch_bounds__(256) void gemm0_hist_kernel(
    const float* __restrict__ X, const ushort* __restrict__ Wt,
    const float* __restrict__ asrc, const float* __restrict__ adst,
    _Float16* __restrict__ Hf, float* __restrict__ hs, float* __restrict__ hd, int N,
    int nGemm, const int* __restrict__ dst, int* __restrict__ cntc, int E, int NB)
{
    const int t = threadIdx.x;
    if (blockIdx.x >= nGemm) {
        __shared__ int lh[256];
        lh[t] = 0;
        __syncthreads();
        const int nb = 256;
        for (int e = (blockIdx.x - nGemm) * 256 + t; e < E; e += nb * 256)
            atomicAdd(&lh[dst[e] >> 8], 1);
        __syncthreads();
        if (t < NB && lh[t]) atomicAdd(&cntc[t], lh[t]);
        return;
    }

    __shared__ ushort Xs[64 * 128];
    __shared__ ushort Bs[128 * 128];
    const int lane = t & 63, wid = t >> 6;
    const int row0 = blockIdx.x * 64;

#pragma unroll
    for (int p = 0; p < 8; ++p) {
        int id = t + p * 256;
        int r = id >> 5, c4g = id & 31;
        int g = row0 + r;
        float4 v = make_float4(0.f, 0.f, 0.f, 0.f);
        if (g < N) v = *(const float4*)&X[(size_t)g * Dd + c4g * 4];
        ushort4 o; o.x = f2bf(v.x); o.y = f2bf(v.y); o.z = f2bf(v.z); o.w = f2bf(v.w);
        int b16 = c4g >> 1, sub = c4g & 1;
        *(ushort4*)&Xs[r * 128 + (((b16 ^ (r & 15)) << 3) | (sub << 2))] = o;
    }
#pragma unroll
    for (int p = 0; p < 8; ++p) {
        int id = t + p * 256;
        int n = id >> 4, b16 = id & 15;
        uint4 v = *(const uint4*)&Wt[(size_t)n * 128 + b16 * 8];
        *(uint4*)&Bs[n * 128 + ((b16 ^ (n & 15)) << 3)] = v;
    }
    __syncthreads();

    f32x4 acc[8];
#pragma unroll
    for (int f = 0; f < 8; ++f) acc[f] = (f32x4){0.f, 0.f, 0.f, 0.f};

#pragma unroll
    for (int kk = 0; kk < 4; ++kk) {
        int ra = wid * 16 + (lane & 15);
        int b16 = (lane >> 4) + kk * 4;
        bf16x8 a = *(bf16x8*)&Xs[ra * 128 + ((b16 ^ (ra & 15)) << 3)];
#pragma unroll
        for (int f = 0; f < 8; ++f) {
            int nb2 = f * 16 + (lane & 15);
            bf16x8 b = *(bf16x8*)&Bs[nb2 * 128 + ((b16 ^ (nb2 & 15)) << 3)];
            acc[f] = __builtin_amdgcn_mfma_f32_16x16x32_bf16(a, b, acc[f], 0, 0, 0);
        }
    }

    float aS[8], aD[8];
#pragma unroll
    for (int f = 0; f < 8; ++f) {
        aS[f] = asrc[(lane & 15) + f * 16];
        aD[f] = adst[(lane & 15) + f * 16];
    }
#pragma unroll
    for (int j = 0; j < 4; ++j) {
        int r = row0 + wid * 16 + (lane >> 4) * 4 + j;
        float ps = 0.f, pd = 0.f;
#pragma unroll
        for (int f = 0; f < 8; ++f) { ps += acc[f][j] * aS[f]; pd += acc[f][j] * aD[f]; }
#pragma unroll
        for (int o = 8; o; o >>= 1) { ps += __shfl_xor(ps, o); pd += __shfl_xor(pd, o); }
        if (r < N) {
#pragma unroll
            for (int f = 0; f < 8; ++f)
                Hf[(size_t)r * Dd + (lane & 15) + f * 16] = (_Float16)acc[f][j];
            if ((lane & 15) == 0) { hs[r] = ps; hd[r] = pd; }
        }
    }
}

// ---------------- layer-1 GEMM (bf16 in) ----------------
__global__ __launch_bounds__(256) void gemm_mfma_bf16(
    const ushort* __restrict__ X, const ushort* __restrict__ Wt,
    const float* __restrict__ asrc, const float* __restrict__ adst,
    _Float16* __restrict__ Hf, float* __restrict__ hs, float* __restrict__ hd, int N)
{
    __shared__ ushort Xs[64 * 128];
    __shared__ ushort Bs[128 * 128];

    const int t = threadIdx.x;
    const int lane = t & 63, wid = t >> 6;
    const int row0 = blockIdx.x * 64;

#pragma unroll
    for (int p = 0; p < 4; ++p) {
        int id = t + p * 256;
        int r = id >> 4, b16 = id & 15;
        int g = row0 + r;
        uint4 v = make_uint4(0, 0, 0, 0);
        if (g < N) v = *(const uint4*)&X[(size_t)g * Dd + b16 * 8];
        *(uint4*)&Xs[r * 128 + ((b16 ^ (r & 15)) << 3)] = v;
    }
#pragma unroll
    for (int p = 0; p < 8; ++p) {
        int id = t + p * 256;
        int n = id >> 4, b16 = id & 15;
        uint4 v = *(const uint4*)&Wt[(size_t)n * 128 + b16 * 8];
        *(uint4*)&Bs[n * 128 + ((b16 ^ (n & 15)) << 3)] = v;
    }
    __syncthreads();

    f32x4 acc[8];
#pragma unroll
    for (int f = 0; f < 8; ++f) acc[f] = (f32x4){0.f, 0.f, 0.f, 0.f};

#pragma unroll
    for (int kk = 0; kk < 4; ++kk) {
        int ra = wid * 16 + (lane & 15);
        int b16 = (lane >> 4) + kk * 4;
        bf16x8 a = *(bf16x8*)&Xs[ra * 128 + ((b16 ^ (ra & 15)) << 3)];
#pragma unroll
        for (int f = 0; f < 8; ++f) {
            int nb = f * 16 + (lane & 15);
            bf16x8 b = *(bf16x8*)&Bs[nb * 128 + ((b16 ^ (nb & 15)) << 3)];
            acc[f] = __builtin_amdgcn_mfma_f32_16x16x32_bf16(a, b, acc[f], 0, 0, 0);
        }
    }

    float aS[8], aD[8];
#pragma unroll
    for (int f = 0; f < 8; ++f) {
        aS[f] = asrc[(lane & 15) + f * 16];
        aD[f] = adst[(lane & 15) + f * 16];
    }
#pragma unroll
    for (int j = 0; j < 4; ++j) {
        int r = row0 + wid * 16 + (lane >> 4) * 4 + j;
        float ps = 0.f, pd = 0.f;
#pragma unroll
        for (int f = 0; f < 8; ++f) { ps += acc[f][j] * aS[f]; pd += acc[f][j] * aD[f]; }
#pragma unroll
        for (int o = 8; o; o >>= 1) { ps += __shfl_xor(ps, o); pd += __shfl_xor(pd, o); }
        if (r < N) {
#pragma unroll
            for (int f = 0; f < 8; ++f)
                Hf[(size_t)r * Dd + (lane & 15) + f * 16] = (_Float16)acc[f][j];
            if ((lane & 15) == 0) { hs[r] = ps; hd[r] = pd; }
        }
    }
}

// ---------------- fused per-node GAT aggregation + BN + ReLU ----------------
// one wave per node; quarter-wave q owns edge stream pos=it*4+q; 16 feat-lanes x 8 f16 feats.
// depth-4 prefetch pipeline, loop unrolled x4 with statically-named slots (no reg spill).
template<bool BF16OUT>
__global__ __launch_bounds__(256) void gat_agg_kernel(
    const int* __restrict__ rowptr, const int* __restrict__ ssrc,
    const float* __restrict__ hs, const float* __restrict__ hd,
    const _Float16* __restrict__ Hf,
    const float* __restrict__ kA, const float* __restrict__ kB,
    void* __restrict__ outv, int N)
{
    const int wid = (blockIdx.x * 256 + threadIdx.x) >> 6;
    if (wid >= N) return;
    const int lane = threadIdx.x & 63;
    const int q = lane >> 4, li = lane & 15;
    const size_t rowO = (size_t)wid * Dd;

    const float hdi = hd[wid];
    float acc[8];
#pragma unroll
    for (int m = 0; m < 8; ++m) acc[m] = 0.f;
    float s = 0.f;

    const int rs = rowptr[wid];
    const int nv = rowptr[wid + 1] - rs;   // >= 1 (self loop included)

    union HU { uint4 u; _Float16 h[8]; };
    HU r0, r1, r2, r3;
    r0.u = r1.u = r2.u = r3.u = make_uint4(0, 0, 0, 0);
    float h0 = 0.f, h1 = 0.f, h2 = 0.f, h3 = 0.f;

    if (q < nv)      { int sj = ssrc[rs + q];      h0 = hs[sj]; r0.u = *(const uint4*)&Hf[(size_t)sj * Dd + li * 8]; }
    if (4 + q < nv)  { int sj = ssrc[rs + 4 + q];  h1 = hs[sj]; r1.u = *(const uint4*)&Hf[(size_t)sj * Dd + li * 8]; }
    if (8 + q < nv)  { int sj = ssrc[rs + 8 + q];  h2 = hs[sj]; r2.u = *(const uint4*)&Hf[(size_t)sj * Dd + li * 8]; }
    if (12 + q < nv) { int sj = ssrc[rs + 12 + q]; h3 = hs[sj]; r3.u = *(const uint4*)&Hf[(size_t)sj * Dd + li * 8]; }

    const int nit = (nv + 3) >> 2;

#define AGG_STEP(RK, HK)                                                 \
    {                                                                    \
        /* issue-early prefetch for slot reuse 4 iterations ahead */     \
        int pn = (it + 4) * 4 + q;                                       \
        uint4 tn = RK.u; float th = HK;                                  \
        if (pn < nv) {                                                   \
            int sj = ssrc[rs + pn];                                      \
            th = hs[sj];                                                 \
            tn = *(const uint4*)&Hf[(size_t)sj * Dd + li * 8];           \
        }                                                                \
        float scv = HK + hdi;                                            \
        scv = scv > 0.f ? scv : NEG_SLOPE * scv;                         \
        float ee = (it * 4 + q < nv) ? __expf(scv) : 0.f;                \
        s += ee;                                                         \
        _Pragma("unroll")                                                \
        for (int m = 0; m < 8; ++m)                                      \
            acc[m] = fmaf((float)RK.h[m], ee, acc[m]);                   \
        RK.u = tn; HK = th;                                              \
    }

    int it = 0;
    while (true) {
        AGG_STEP(r0, h0); if (++it >= nit) break;
        AGG_STEP(r1, h1); if (++it >= nit) break;
        AGG_STEP(r2, h2); if (++it >= nit) break;
        AGG_STEP(r3, h3); if (++it >= nit) break;
    }
#undef AGG_STEP

    // cross-quarter reduce (values uniform within each quarter)
#pragma unroll
    for (int m = 0; m < 8; ++m) {
        acc[m] += __shfl_xor(acc[m], 16);
        acc[m] += __shfl_xor(acc[m], 32);
    }
    s += __shfl_xor(s, 16);
    s += __shfl_xor(s, 32);

    if (q == 0) {
        float inv = 1.0f / s;
        int c0 = li * 8;
        float4 ka0 = *(const float4*)&kA[c0],     ka1 = *(const float4*)&kA[c0 + 4];
        float4 kb0 = *(const float4*)&kB[c0],     kb1 = *(const float4*)&kB[c0 + 4];
        float o[8];
        o[0] = fmaxf(acc[0] * inv * ka0.x + kb0.x, 0.f);
        o[1] = fmaxf(acc[1] * inv * ka0.y + kb0.y, 0.f);
        o[2] = fmaxf(acc[2] * inv * ka0.z + kb0.z, 0.f);
        o[3] = fmaxf(acc[3] * inv * ka0.w + kb0.w, 0.f);
        o[4] = fmaxf(acc[4] * inv * ka1.x + kb1.x, 0.f);
        o[5] = fmaxf(acc[5] * inv * ka1.y + kb1.y, 0.f);
        o[6] = fmaxf(acc[6] * inv * ka1.z + kb1.z, 0.f);
        o[7] = fmaxf(acc[7] * inv * ka1.w + kb1.w, 0.f);
        if constexpr (BF16OUT) {
            ushort* out = (ushort*)outv;
            uint4 pk;
#pragma unroll
            for (int k = 0; k < 4; ++k)
                ((unsigned*)&pk)[k] = (unsigned)f2bf(o[2 * k]) | ((unsigned)f2bf(o[2 * k + 1]) << 16);
            *(uint4*)&out[rowO + c0] = pk;
        } else {
            float* out = (float*)outv;
            *(float4*)&out[rowO + c0]     = make_float4(o[0], o[1], o[2], o[3]);
            *(float4*)&out[rowO + c0 + 4] = make_float4(o[4], o[5], o[6], o[7]);
        }
    }
}

extern "C" void kernel_launch(void* const* d_in, const int* in_sizes, int n_in,
                              void* d_out, int out_size, void* d_ws, size_t ws_size,
                              hipStream_t stream)
{
    const float* x     = (const float*)d_in[0];
    const int*   ei    = (const int*)d_in[1];
    const float* Ws    = (const float*)d_in[2];
    const float* a_src = (const float*)d_in[3];
    const float* a_dst = (const float*)d_in[4];
    const float* bias  = (const float*)d_in[5];
    const float* gamma = (const float*)d_in[6];
    const float* beta  = (const float*)d_in[7];
    const float* mean  = (const float*)d_in[8];
    const float* var   = (const float*)d_in[9];
    float* out = (float*)d_out;
    float* ws  = (float*)d_ws;

    const int N = in_sizes[0] / Dd;       // 50000 (< 65536: packed-edge format)
    const int E = in_sizes[1] / 2;
    const int Etot = E + N;               // + self loops
    const int NB = (N + 255) >> 8;
    const int* src = ei;
    const int* dst = ei + E;

    float*    hs   = ws;                                  // N
    float*    hd   = hs + N;                              // N
    _Float16* Hf   = (_Float16*)(hd + N);                 // N*128 f16
    ushort*   xmid = (ushort*)(Hf + (size_t)N * Dd);      // N*128 bf16
    ushort*   WtB  = xmid + (size_t)N * Dd;               // 2*128*128 bf16
    float*    kAB  = (float*)(WtB + 2 * Dd * Dd);         // 512 f32: kA[256] | kB[256]
    int* rowptr  = (int*)(kAB + 512);                     // N+1
    int* cntc    = rowptr + (N + 1);                      // 256
    int* base    = cntc + 256;                            // 257
    int* cursor  = base + 257;                            // 256
    unsigned* gpart = (unsigned*)(cursor + 256);          // E
    int* ssrc    = (int*)(gpart + E);                     // Etot

    const int gemm_blocks = (N + 63) / 64;
    const int part_blocks = (E + 4095) / 4096;
    const int agg_blocks  = (N * 64 + 255) / 256;

    // ---- prep (zero cntc, W->bf16, BN consts) ----
    wprep_zero_kernel<<<3, 256, 0, stream>>>(Ws, WtB, cntc, bias, gamma, beta, mean, var,
                                             kAB, kAB + 256);
    // ---- layer-0 GEMM overlapped with coarse hist ----
    gemm0_hist_kernel<<<gemm_blocks + 256, 256, 0, stream>>>(
        x, WtB, a_src, a_dst, Hf, hs, hd, N, gemm_blocks, dst, cntc, E, NB);
    // ---- CSR build (shared by both layers) ----
    coarse_scan_kernel<<<1, 256, 0, stream>>>(cntc, base, cursor, NB, E);
    partition_kernel<<<part_blocks, 256, 0, stream>>>(src, dst, cursor, gpart, E);
    bucket_csr_kernel<<<NB, 256, 0, stream>>>(gpart, base, rowptr, ssrc, N, NB, Etot);

    // ---- layer 0 aggregation -> xmid (bf16) ----
    gat_agg_kernel<true><<<agg_blocks, 256, 0, stream>>>(
        rowptr, ssrc, hs, hd, Hf, kAB, kAB + 256, (void*)xmid, N);

    // ---- layer 1 ----
    gemm_mfma_bf16<<<gemm_blocks, 256, 0, stream>>>(
        xmid, WtB + (size_t)Dd * Dd, a_src + Dd, a_dst + Dd, Hf, hs, hd, N);
    gat_agg_kernel<false><<<agg_blocks, 256, 0, stream>>>(
        rowptr, ssrc, hs, hd, Hf, kAB + 128, kAB + 256 + 128, (void*)out, N);
}

// Round 11
// 233.919 us; speedup vs baseline: 1.2133x; 1.2133x over previous
//
#include <hip/hip_runtime.h>

constexpr int Dd = 128;
constexpr float BN_EPS = 1e-12f;
constexpr float NEG_SLOPE = 0.2f;

using bf16x8 = __attribute__((ext_vector_type(8))) short;
using f32x4  = __attribute__((ext_vector_type(4))) float;

__device__ __forceinline__ ushort f2bf(float f) {
    unsigned u = __float_as_uint(f);
    return (ushort)((u + 0x7fffu + ((u >> 16) & 1u)) >> 16);
}
__device__ __forceinline__ float lrelu(float x) { return x > 0.f ? x : NEG_SLOPE * x; }

// ---------------- W prep + coarse-cnt zero + BN-const precompute ----------------
__global__ __launch_bounds__(256) void wprep_zero_kernel(
    const float* __restrict__ W, ushort* __restrict__ Wt, int* __restrict__ cntc,
    const float* __restrict__ bias, const float* __restrict__ gamma,
    const float* __restrict__ beta, const float* __restrict__ mean,
    const float* __restrict__ var, float* __restrict__ kA, float* __restrict__ kB)
{
    int t = threadIdx.x;
    if (blockIdx.x >= 2) {           // block 2: zero coarse counters + BN consts (both layers)
        cntc[t] = 0;
        float sc = gamma[t] * rsqrtf(var[t] + BN_EPS);
        kA[t] = sc;
        kB[t] = (bias[t] - mean[t]) * sc + beta[t];
        return;
    }
    __shared__ float lds[32][33];
    const float* Wl = W + (size_t)blockIdx.x * Dd * Dd;
    ushort* Wo = Wt + (size_t)blockIdx.x * Dd * Dd;
    int r = t >> 3, c4 = (t & 7) << 2;
    for (int tk = 0; tk < 4; ++tk)
    for (int tn = 0; tn < 4; ++tn) {
        int k0 = tk * 32, n0 = tn * 32;
        float4 v = *(const float4*)&Wl[(size_t)(k0 + r) * Dd + n0 + c4];
        lds[r][c4] = v.x; lds[r][c4 + 1] = v.y; lds[r][c4 + 2] = v.z; lds[r][c4 + 3] = v.w;
        __syncthreads();
        ushort4 o;
        o.x = f2bf(lds[c4 + 0][r]); o.y = f2bf(lds[c4 + 1][r]);
        o.z = f2bf(lds[c4 + 2][r]); o.w = f2bf(lds[c4 + 3][r]);
        *(ushort4*)&Wo[(size_t)(n0 + r) * Dd + k0 + c4] = o;
        __syncthreads();
    }
}

// ---------------- coarse scan (1 block) ----------------
__global__ __launch_bounds__(256) void coarse_scan_kernel(
    const int* __restrict__ cntc, int* __restrict__ base,
    int* __restrict__ cursor, int NB, int E)
{
    __shared__ int lds[256];
    int t = threadIdx.x;
    int v0 = (t < NB) ? cntc[t] : 0;
    lds[t] = v0;
    __syncthreads();
    for (int o = 1; o < 256; o <<= 1) {
        int v = (t >= o) ? lds[t - o] : 0;
        __syncthreads();
        lds[t] += v;
        __syncthreads();
    }
    int excl = lds[t] - v0;
    if (t < NB) { base[t] = excl; cursor[t] = excl; }
    if (t == 0) base[NB] = E;
}

// ---------------- partition: stage by bucket in LDS, coalesced flush ----------------
// packed = src | dst_lo<<16 | bucket<<24  (valid because N < 65536)
__global__ __launch_bounds__(256) void partition_kernel(
    const int* __restrict__ src, const int* __restrict__ dst,
    int* __restrict__ cursor, unsigned* __restrict__ gpart, int E)
{
    __shared__ int h[256], lb[256], gs[256], cur[256];
    __shared__ unsigned staged[4096];
    const int t = threadIdx.x;
    const int c0 = blockIdx.x * 4096;
    const int count = min(4096, E - c0);

    h[t] = 0; cur[t] = 0;
    __syncthreads();
#pragma unroll
    for (int j = 0; j < 16; ++j) {
        int idx = j * 256 + t;
        if (idx < count) atomicAdd(&h[dst[c0 + idx] >> 8], 1);
    }
    __syncthreads();
    {
        int v0 = h[t];
        lb[t] = v0;
        __syncthreads();
        for (int o = 1; o < 256; o <<= 1) {
            int v = (t >= o) ? lb[t - o] : 0;
            __syncthreads();
            lb[t] += v;
            __syncthreads();
        }
        lb[t] -= v0;
    }
    if (h[t]) gs[t] = atomicAdd(&cursor[t], h[t]);
    __syncthreads();
#pragma unroll
    for (int j = 0; j < 16; ++j) {
        int idx = j * 256 + t;
        if (idx < count) {
            int d = dst[c0 + idx], s = src[c0 + idx];
            int b = d >> 8;
            int pos = lb[b] + atomicAdd(&cur[b], 1);
            staged[pos] = (unsigned)s | ((unsigned)(d & 255) << 16) | ((unsigned)b << 24);
        }
    }
    __syncthreads();
#pragma unroll
    for (int j = 0; j < 16; ++j) {
        int idx = j * 256 + t;
        if (idx < count) {
            unsigned p = staged[idx];
            int b = p >> 24;
            gpart[gs[b] + (idx - lb[b])] = p;
        }
    }
}

// ---------------- per-bucket CSR finalize: rowptr + self-loops + ssrc ----------------
__global__ __launch_bounds__(256) void bucket_csr_kernel(
    const unsigned* __restrict__ gpart, const int* __restrict__ base,
    int* __restrict__ rowptr, int* __restrict__ ssrc, int N, int NB, int Etot)
{
    __shared__ int h[256], lb[256], cur[256];
    const int t = threadIdx.x;
    const int b = blockIdx.x;
    const int cb = base[b], ce = base[b + 1];
    const int cb2 = cb + b * 256;   // +1 self edge per node in earlier buckets
    const int cnt = ce - cb;

    h[t] = 0; cur[t] = 0;
    __syncthreads();
    for (int o = t; o < cnt; o += 256)
        atomicAdd(&h[(gpart[cb + o] >> 16) & 255], 1);
    __syncthreads();
    {
        int v0 = h[t];
        lb[t] = v0;
        __syncthreads();
        for (int o = 1; o < 256; o <<= 1) {
            int v = (t >= o) ? lb[t - o] : 0;
            __syncthreads();
            lb[t] += v;
            __syncthreads();
        }
        lb[t] -= v0;
    }
    int n0 = b * 256 + t;
    if (n0 < N) {
        int rp = cb2 + lb[t] + t;
        rowptr[n0] = rp;
        ssrc[rp] = n0;       // self-loop first
    }
    if (b == 0 && t == 0) rowptr[N] = Etot;
    __syncthreads();
    for (int o = t; o < cnt; o += 256) {
        unsigned p = gpart[cb + o];
        int n = (p >> 16) & 255;
        int pos = lb[n] + atomicAdd(&cur[n], 1);
        ssrc[cb2 + pos + n + 1] = (int)(p & 0xFFFFu);
    }
}

// ---------------- layer-0 GEMM (f32 in) fused with coarse hist ----------------
// blocks [0,nGemm): Hf = f16(x@W0), hs/hd; blocks [nGemm, nGemm+256): dst histogram.
__global__ __launch_bounds__(256) void gemm0_hist_kernel(
    const float* __restrict__ X, const ushort* __restrict__ Wt,
    const float* __restrict__ asrc, const float* __restrict__ adst,
    _Float16* __restrict__ Hf, float* __restrict__ hs, float* __restrict__ hd, int N,
    int nGemm, const int* __restrict__ dst, int* __restrict__ cntc, int E, int NB)
{
    const int t = threadIdx.x;
    if (blockIdx.x >= nGemm) {
        __shared__ int lh[256];
        lh[t] = 0;
        __syncthreads();
        const int nb = 256;
        for (int e = (blockIdx.x - nGemm) * 256 + t; e < E; e += nb * 256)
            atomicAdd(&lh[dst[e] >> 8], 1);
        __syncthreads();
        if (t < NB && lh[t]) atomicAdd(&cntc[t], lh[t]);
        return;
    }

    __shared__ ushort Xs[64 * 128];
    __shared__ ushort Bs[128 * 128];
    const int lane = t & 63, wid = t >> 6;
    const int row0 = blockIdx.x * 64;

#pragma unroll
    for (int p = 0; p < 8; ++p) {
        int id = t + p * 256;
        int r = id >> 5, c4g = id & 31;
        int g = row0 + r;
        float4 v = make_float4(0.f, 0.f, 0.f, 0.f);
        if (g < N) v = *(const float4*)&X[(size_t)g * Dd + c4g * 4];
        ushort4 o; o.x = f2bf(v.x); o.y = f2bf(v.y); o.z = f2bf(v.z); o.w = f2bf(v.w);
        int b16 = c4g >> 1, sub = c4g & 1;
        *(ushort4*)&Xs[r * 128 + (((b16 ^ (r & 15)) << 3) | (sub << 2))] = o;
    }
#pragma unroll
    for (int p = 0; p < 8; ++p) {
        int id = t + p * 256;
        int n = id >> 4, b16 = id & 15;
        uint4 v = *(const uint4*)&Wt[(size_t)n * 128 + b16 * 8];
        *(uint4*)&Bs[n * 128 + ((b16 ^ (n & 15)) << 3)] = v;
    }
    __syncthreads();

    f32x4 acc[8];
#pragma unroll
    for (int f = 0; f < 8; ++f) acc[f] = (f32x4){0.f, 0.f, 0.f, 0.f};

#pragma unroll
    for (int kk = 0; kk < 4; ++kk) {
        int ra = wid * 16 + (lane & 15);
        int b16 = (lane >> 4) + kk * 4;
        bf16x8 a = *(bf16x8*)&Xs[ra * 128 + ((b16 ^ (ra & 15)) << 3)];
#pragma unroll
        for (int f = 0; f < 8; ++f) {
            int nb2 = f * 16 + (lane & 15);
            bf16x8 b = *(bf16x8*)&Bs[nb2 * 128 + ((b16 ^ (nb2 & 15)) << 3)];
            acc[f] = __builtin_amdgcn_mfma_f32_16x16x32_bf16(a, b, acc[f], 0, 0, 0);
        }
    }

    float aS[8], aD[8];
#pragma unroll
    for (int f = 0; f < 8; ++f) {
        aS[f] = asrc[(lane & 15) + f * 16];
        aD[f] = adst[(lane & 15) + f * 16];
    }
#pragma unroll
    for (int j = 0; j < 4; ++j) {
        int r = row0 + wid * 16 + (lane >> 4) * 4 + j;
        float ps = 0.f, pd = 0.f;
#pragma unroll
        for (int f = 0; f < 8; ++f) { ps += acc[f][j] * aS[f]; pd += acc[f][j] * aD[f]; }
#pragma unroll
        for (int o = 8; o; o >>= 1) { ps += __shfl_xor(ps, o); pd += __shfl_xor(pd, o); }
        if (r < N) {
#pragma unroll
            for (int f = 0; f < 8; ++f)
                Hf[(size_t)r * Dd + (lane & 15) + f * 16] = (_Float16)acc[f][j];
            if ((lane & 15) == 0) { hs[r] = ps; hd[r] = pd; }
        }
    }
}

// ---------------- layer-1 GEMM (bf16 in) ----------------
__global__ __launch_bounds__(256) void gemm_mfma_bf16(
    const ushort* __restrict__ X, const ushort* __restrict__ Wt,
    const float* __restrict__ asrc, const float* __restrict__ adst,
    _Float16* __restrict__ Hf, float* __restrict__ hs, float* __restrict__ hd, int N)
{
    __shared__ ushort Xs[64 * 128];
    __shared__ ushort Bs[128 * 128];

    const int t = threadIdx.x;
    const int lane = t & 63, wid = t >> 6;
    const int row0 = blockIdx.x * 64;

#pragma unroll
    for (int p = 0; p < 4; ++p) {
        int id = t + p * 256;
        int r = id >> 4, b16 = id & 15;
        int g = row0 + r;
        uint4 v = make_uint4(0, 0, 0, 0);
        if (g < N) v = *(const uint4*)&X[(size_t)g * Dd + b16 * 8];
        *(uint4*)&Xs[r * 128 + ((b16 ^ (r & 15)) << 3)] = v;
    }
#pragma unroll
    for (int p = 0; p < 8; ++p) {
        int id = t + p * 256;
        int n = id >> 4, b16 = id & 15;
        uint4 v = *(const uint4*)&Wt[(size_t)n * 128 + b16 * 8];
        *(uint4*)&Bs[n * 128 + ((b16 ^ (n & 15)) << 3)] = v;
    }
    __syncthreads();

    f32x4 acc[8];
#pragma unroll
    for (int f = 0; f < 8; ++f) acc[f] = (f32x4){0.f, 0.f, 0.f, 0.f};

#pragma unroll
    for (int kk = 0; kk < 4; ++kk) {
        int ra = wid * 16 + (lane & 15);
        int b16 = (lane >> 4) + kk * 4;
        bf16x8 a = *(bf16x8*)&Xs[ra * 128 + ((b16 ^ (ra & 15)) << 3)];
#pragma unroll
        for (int f = 0; f < 8; ++f) {
            int nb = f * 16 + (lane & 15);
            bf16x8 b = *(bf16x8*)&Bs[nb * 128 + ((b16 ^ (nb & 15)) << 3)];
            acc[f] = __builtin_amdgcn_mfma_f32_16x16x32_bf16(a, b, acc[f], 0, 0, 0);
        }
    }

    float aS[8], aD[8];
#pragma unroll
    for (int f = 0; f < 8; ++f) {
        aS[f] = asrc[(lane & 15) + f * 16];
        aD[f] = adst[(lane & 15) + f * 16];
    }
#pragma unroll
    for (int j = 0; j < 4; ++j) {
        int r = row0 + wid * 16 + (lane >> 4) * 4 + j;
        float ps = 0.f, pd = 0.f;
#pragma unroll
        for (int f = 0; f < 8; ++f) { ps += acc[f][j] * aS[f]; pd += acc[f][j] * aD[f]; }
#pragma unroll
        for (int o = 8; o; o >>= 1) { ps += __shfl_xor(ps, o); pd += __shfl_xor(pd, o); }
        if (r < N) {
#pragma unroll
            for (int f = 0; f < 8; ++f)
                Hf[(size_t)r * Dd + (lane & 15) + f * 16] = (_Float16)acc[f][j];
            if ((lane & 15) == 0) { hs[r] = ps; hd[r] = pd; }
        }
    }
}

// ---------------- fused per-node GAT aggregation + BN + ReLU (R9-exact, depth-2) ----------------
// one wave per node; quarter-wave q owns edge stream pos=it*4+q; 16 feat-lanes x 8 f16 feats.
// no max-subtraction (scores bounded -> fp32 exp safe); self-loops are real CSR edges.
template<bool BF16OUT>
__global__ __launch_bounds__(256) void gat_agg_kernel(
    const int* __restrict__ rowptr, const int* __restrict__ ssrc,
    const float* __restrict__ hs, const float* __restrict__ hd,
    const _Float16* __restrict__ Hf,
    const float* __restrict__ kA, const float* __restrict__ kB,
    void* __restrict__ outv, int N)
{
    const int wid = (blockIdx.x * 256 + threadIdx.x) >> 6;
    if (wid >= N) return;
    const int lane = threadIdx.x & 63;
    const int q = lane >> 4, li = lane & 15;
    const size_t rowO = (size_t)wid * Dd;

    const float hdi = hd[wid];
    float acc[8];
#pragma unroll
    for (int m = 0; m < 8; ++m) acc[m] = 0.f;
    float s = 0.f;

    const int rs = rowptr[wid];
    const int nv = rowptr[wid + 1] - rs;   // >= 1 (self loop included)

    union HU { uint4 u; _Float16 h[8]; };
    HU r0, r1; r0.u = make_uint4(0,0,0,0); r1.u = make_uint4(0,0,0,0);
    float h0 = 0.f, h1 = 0.f;
    if (q < nv) {
        int sj = ssrc[rs + q];
        h0 = hs[sj];
        r0.u = *(const uint4*)&Hf[(size_t)sj * Dd + li * 8];
    }
    if (4 + q < nv) {
        int sj = ssrc[rs + 4 + q];
        h1 = hs[sj];
        r1.u = *(const uint4*)&Hf[(size_t)sj * Dd + li * 8];
    }

    const int nit = (nv + 3) >> 2;
    for (int it = 0; it < nit; ++it) {
        float scv = h0 + hdi;
        scv = scv > 0.f ? scv : NEG_SLOPE * scv;
        float ee = (it * 4 + q < nv) ? __expf(scv) : 0.f;
        s += ee;
        HU rc = r0;
        r0 = r1; h0 = h1;
        int pn = (it + 2) * 4 + q;
        if (pn < nv) {
            int sj = ssrc[rs + pn];
            h1 = hs[sj];
            r1.u = *(const uint4*)&Hf[(size_t)sj * Dd + li * 8];
        }
#pragma unroll
        for (int m = 0; m < 8; ++m)
            acc[m] = fmaf((float)rc.h[m], ee, acc[m]);   // v_fma_mix_f32
    }

    // cross-quarter reduce (values uniform within each quarter)
#pragma unroll
    for (int m = 0; m < 8; ++m) {
        acc[m] += __shfl_xor(acc[m], 16);
        acc[m] += __shfl_xor(acc[m], 32);
    }
    s += __shfl_xor(s, 16);
    s += __shfl_xor(s, 32);

    if (q == 0) {
        float inv = 1.0f / s;
        int c0 = li * 8;
        float4 ka0 = *(const float4*)&kA[c0],     ka1 = *(const float4*)&kA[c0 + 4];
        float4 kb0 = *(const float4*)&kB[c0],     kb1 = *(const float4*)&kB[c0 + 4];
        float o[8];
        o[0] = fmaxf(acc[0] * inv * ka0.x + kb0.x, 0.f);
        o[1] = fmaxf(acc[1] * inv * ka0.y + kb0.y, 0.f);
        o[2] = fmaxf(acc[2] * inv * ka0.z + kb0.z, 0.f);
        o[3] = fmaxf(acc[3] * inv * ka0.w + kb0.w, 0.f);
        o[4] = fmaxf(acc[4] * inv * ka1.x + kb1.x, 0.f);
        o[5] = fmaxf(acc[5] * inv * ka1.y + kb1.y, 0.f);
        o[6] = fmaxf(acc[6] * inv * ka1.z + kb1.z, 0.f);
        o[7] = fmaxf(acc[7] * inv * ka1.w + kb1.w, 0.f);
        if constexpr (BF16OUT) {
            ushort* out = (ushort*)outv;
            uint4 pk;
#pragma unroll
            for (int k = 0; k < 4; ++k)
                ((unsigned*)&pk)[k] = (unsigned)f2bf(o[2 * k]) | ((unsigned)f2bf(o[2 * k + 1]) << 16);
            *(uint4*)&out[rowO + c0] = pk;
        } else {
            float* out = (float*)outv;
            *(float4*)&out[rowO + c0]     = make_float4(o[0], o[1], o[2], o[3]);
            *(float4*)&out[rowO + c0 + 4] = make_float4(o[4], o[5], o[6], o[7]);
        }
    }
}

extern "C" void kernel_launch(void* const* d_in, const int* in_sizes, int n_in,
                              void* d_out, int out_size, void* d_ws, size_t ws_size,
                              hipStream_t stream)
{
    const float* x     = (const float*)d_in[0];
    const int*   ei    = (const int*)d_in[1];
    const float* Ws    = (const float*)d_in[2];
    const float* a_src = (const float*)d_in[3];
    const float* a_dst = (const float*)d_in[4];
    const float* bias  = (const float*)d_in[5];
    const float* gamma = (const float*)d_in[6];
    const float* beta  = (const float*)d_in[7];
    const float* mean  = (const float*)d_in[8];
    const float* var   = (const float*)d_in[9];
    float* out = (float*)d_out;
    float* ws  = (float*)d_ws;

    const int N = in_sizes[0] / Dd;       // 50000 (< 65536: packed-edge format)
    const int E = in_sizes[1] / 2;
    const int Etot = E + N;               // + self loops
    const int NB = (N + 255) >> 8;
    const int* src = ei;
    const int* dst = ei + E;

    float*    hs   = ws;                                  // N
    float*    hd   = hs + N;                              // N
    _Float16* Hf   = (_Float16*)(hd + N);                 // N*128 f16
    ushort*   xmid = (ushort*)(Hf + (size_t)N * Dd);      // N*128 bf16
    ushort*   WtB  = xmid + (size_t)N * Dd;               // 2*128*128 bf16
    float*    kAB  = (float*)(WtB + 2 * Dd * Dd);         // 512 f32: kA[256] | kB[256]
    int* rowptr  = (int*)(kAB + 512);                     // N+1
    int* cntc    = rowptr + (N + 1);                      // 256
    int* base    = cntc + 256;                            // 257
    int* cursor  = base + 257;                            // 256
    unsigned* gpart = (unsigned*)(cursor + 256);          // E
    int* ssrc    = (int*)(gpart + E);                     // Etot

    const int gemm_blocks = (N + 63) / 64;
    const int part_blocks = (E + 4095) / 4096;
    const int agg_blocks  = (N * 64 + 255) / 256;

    // ---- prep (zero cntc, W->bf16, BN consts) ----
    wprep_zero_kernel<<<3, 256, 0, stream>>>(Ws, WtB, cntc, bias, gamma, beta, mean, var,
                                             kAB, kAB + 256);
    // ---- layer-0 GEMM overlapped with coarse hist ----
    gemm0_hist_kernel<<<gemm_blocks + 256, 256, 0, stream>>>(
        x, WtB, a_src, a_dst, Hf, hs, hd, N, gemm_blocks, dst, cntc, E, NB);
    // ---- CSR build (shared by both layers) ----
    coarse_scan_kernel<<<1, 256, 0, stream>>>(cntc, base, cursor, NB, E);
    partition_kernel<<<part_blocks, 256, 0, stream>>>(src, dst, cursor, gpart, E);
    bucket_csr_kernel<<<NB, 256, 0, stream>>>(gpart, base, rowptr, ssrc, N, NB, Etot);

    // ---- layer 0 aggregation -> xmid (bf16) ----
    gat_agg_kernel<true><<<agg_blocks, 256, 0, stream>>>(
        rowptr, ssrc, hs, hd, Hf, kAB, kAB + 256, (void*)xmid, N);

    // ---- layer 1 ----
    gemm_mfma_bf16<<<gemm_blocks, 256, 0, stream>>>(
        xmid, WtB + (size_t)Dd * Dd, a_src + Dd, a_dst + Dd, Hf, hs, hd, N);
    gat_agg_kernel<false><<<agg_blocks, 256, 0, stream>>>(
        rowptr, ssrc, hs, hd, Hf, kAB + 128, kAB + 256 + 128, (void*)out, N);
}